// Round 1
// baseline (131.424 us; speedup 1.0000x reference)
//
#include <hip/hip_runtime.h>
#include <math.h>

#define EPS 1e-9f

constexpr int Bn = 1024, Dn = 512, Un = 512;
constexpr int BM = 64;      // rows of B per block
constexpr int BU = 64;      // cols of U per block
constexpr int DK = 32;      // k-chunk staged in LDS
constexpr int SPLITD = 4;   // D split across blocks (atomicAdd combine)
constexpr int DPB = Dn / SPLITD;    // 128 d per block
constexpr int NCHUNK = DPB / DK;    // 4 chunks

__global__ __launch_bounds__(256) void init_out(const float* __restrict__ bias,
                                                float* __restrict__ out, int n) {
    int i = blockIdx.x * 256 + threadIdx.x;
    if (i < n) out[i] = bias[i & (Un - 1)];
}

__global__ __launch_bounds__(256) void power_layer(
    const float* __restrict__ x, const float* __restrict__ w,
    const float* __restrict__ p, float* __restrict__ out)
{
    // d-major LDS layout: inner loop reads float4 over rows/cols (conflict-free),
    // per-d address step is a 256B immediate offset for ds_read_b128.
    __shared__ float sL[DK][BM];   // Lenc = sign(neg) * (log2|x+eps| + 64)
    __shared__ float sP[DK][BU];   // p
    __shared__ float sW[DK][BU];   // w
    __shared__ float sWX[DK][BU];  // odd(p) ? -w : w

    const int tid = threadIdx.x;
    const int tx = tid & 15;        // col group
    const int ty = tid >> 4;        // row group
    const int ub = blockIdx.x * BU;
    const int bb = blockIdx.y * BM;
    const int d0 = blockIdx.z * DPB;

    float acc[4][4] = {};

    for (int ch = 0; ch < NCHUNK; ++ch) {
        const int db = d0 + ch * DK;

        // ---- stage x tile -> sL (64 rows x 32 d), transposed to [d][row] ----
        // 512 float4 loads, 2 per thread; coalesced along d.
        {
            int t = tid;
            #pragma unroll
            for (int it = 0; it < 2; ++it, t += 256) {
                const int r  = t >> 3;            // 0..63
                const int dq = (t & 7) << 2;      // 0,4,...,28
                const float4 xv = *reinterpret_cast<const float4*>(
                    &x[(size_t)(bb + r) * Dn + db + dq]);
                const float* xs = reinterpret_cast<const float*>(&xv);
                #pragma unroll
                for (int j = 0; j < 4; ++j) {
                    const float xe = xs[j] + EPS;
                    const float La = __builtin_amdgcn_logf(fabsf(xe)) + 64.0f;
                    sL[dq + j][r] = (xe < 0.0f) ? -La : La;
                }
            }
        }
        // ---- stage p,w tiles (32 d x 64 u), natural layout, float4 writes ----
        {
            int t = tid;
            #pragma unroll
            for (int it = 0; it < 2; ++it, t += 256) {
                const int d  = t >> 4;            // 0..31
                const int uq = (t & 15) << 2;     // 0..60
                const size_t gi = (size_t)(db + d) * Un + ub + uq;
                const float4 pv = *reinterpret_cast<const float4*>(&p[gi]);
                const float4 wv = *reinterpret_cast<const float4*>(&w[gi]);
                const float* ps = reinterpret_cast<const float*>(&pv);
                const float* wsv = reinterpret_cast<const float*>(&wv);
                float4 wxv;
                float* wxs = reinterpret_cast<float*>(&wxv);
                #pragma unroll
                for (int j = 0; j < 4; ++j) {
                    const bool odd = (fmodf(ps[j], 2.0f) != 0.0f);
                    wxs[j] = odd ? -wsv[j] : wsv[j];
                }
                *reinterpret_cast<float4*>(&sP[d][uq])  = pv;
                *reinterpret_cast<float4*>(&sW[d][uq])  = wv;
                *reinterpret_cast<float4*>(&sWX[d][uq]) = wxv;
            }
        }
        __syncthreads();

        #pragma unroll 8
        for (int d = 0; d < DK; ++d) {
            const float4 Lv  = *reinterpret_cast<const float4*>(&sL[d][ty * 4]);
            const float4 Pv  = *reinterpret_cast<const float4*>(&sP[d][tx * 4]);
            const float4 Wv  = *reinterpret_cast<const float4*>(&sW[d][tx * 4]);
            const float4 WXv = *reinterpret_cast<const float4*>(&sWX[d][tx * 4]);
            const float* Ls  = reinterpret_cast<const float*>(&Lv);
            const float* Ps  = reinterpret_cast<const float*>(&Pv);
            const float* Ws  = reinterpret_cast<const float*>(&Wv);
            const float* WXs = reinterpret_cast<const float*>(&WXv);
            #pragma unroll
            for (int r = 0; r < 4; ++r) {
                const float Lenc = Ls[r];
                const float L    = fabsf(Lenc) - 64.0f;
                const bool  neg  = Lenc < 0.0f;
                #pragma unroll
                for (int c = 0; c < 4; ++c) {
                    const float tt  = Ps[c] * L;
                    const float e   = __builtin_amdgcn_exp2f(tt);
                    const float wgt = neg ? WXs[c] : Ws[c];
                    acc[r][c] = fmaf(wgt, e, acc[r][c]);
                }
            }
        }
        __syncthreads();
    }

    // combine split-D partials
    #pragma unroll
    for (int r = 0; r < 4; ++r) {
        const int row = bb + ty * 4 + r;
        #pragma unroll
        for (int c = 0; c < 4; ++c) {
            atomicAdd(&out[(size_t)row * Un + ub + tx * 4 + c], acc[r][c]);
        }
    }
}

extern "C" void kernel_launch(void* const* d_in, const int* in_sizes, int n_in,
                              void* d_out, int out_size, void* d_ws, size_t ws_size,
                              hipStream_t stream) {
    const float* x = (const float*)d_in[0];
    const float* w = (const float*)d_in[1];
    const float* p = (const float*)d_in[2];
    const float* b = (const float*)d_in[3];
    float* out = (float*)d_out;

    // out = bias (d_out is poisoned before every launch)
    init_out<<<dim3((out_size + 255) / 256), dim3(256), 0, stream>>>(b, out, out_size);

    // main contraction, split-D atomically combined
    power_layer<<<dim3(Un / BU, Bn / BM, SPLITD), dim3(256), 0, stream>>>(x, w, p, out);
}